// Round 6
// baseline (180.797 us; speedup 1.0000x reference)
//
#include <hip/hip_runtime.h>

#define NN 16
#define KK 256
#define TT 1000
#define MM 384
#define TCH 16     // t's per k_score block (63 blocks, tail-guarded)
#define TOB 16     // t's per k_out block
#define TP 1008    // padded T stride for E_T (4032 B, 16B-aligned rows)

__device__ __forceinline__ float fast_rcp(float x) { return __builtin_amdgcn_rcpf(x); }
__device__ __forceinline__ float silu_f(float x) {
    float e = __expf(-x);
    return x * fast_rcp(1.0f + e);
}

// ---------------- K1: durations + exclusive cumsum ----------------
__global__ void k_scan(const float* __restrict__ dur_out,
                       float* __restrict__ wsS, float* __restrict__ wsD) {
    __shared__ float lds[KK];
    int n = blockIdx.x, k = threadIdx.x;
    float d = __expf(dur_out[n * KK + k]) - 1.0f;
    d = fmaxf(d, 0.0f);
    lds[k] = d;
    __syncthreads();
    float run = d;
    for (int off = 1; off < KK; off <<= 1) {
        float v = (k >= off) ? lds[k - off] : 0.0f;
        __syncthreads();
        run += v;
        lds[k] = run;
        __syncthreads();
    }
    wsS[n * KK + k] = run - d;
    wsD[n * KK + k] = d;
}

// ---------------- K2: conv1d(3,same)+BN+silu, fold into q1/qA ----------------
// grid (16 kc, 16 n): 256 blocks -> all CUs busy. 256 thr = 16 k x 16 mg (24 m each).
__global__ __launch_bounds__(256) void k_conv(
    const float* __restrict__ V, const float* __restrict__ conv_w,
    const float* __restrict__ conv_b, const float* __restrict__ bn_g,
    const float* __restrict__ bn_b, const float* __restrict__ bn_m,
    const float* __restrict__ bn_v, const float* __restrict__ w1,
    const float* __restrict__ b1, const float* __restrict__ aw1,
    const float* __restrict__ ab1, const float* __restrict__ wsD,
    float* __restrict__ wsQ1, float* __restrict__ wsQA) {
    __shared__ __align__(16) float wt[3 * MM * 8];   // 36 KB conv weights
    __shared__ float red[16 * 16 * 8];               // 8 KB partials
    __shared__ float cvl[16 * 8];
    __shared__ float dl[16];
    int tid = threadIdx.x;
    int kc = blockIdx.x, n = blockIdx.y;
    for (int i = tid; i < 3 * MM * 8; i += 256) wt[i] = conv_w[i];
    __syncthreads();

    int kk = tid & 15, mg = tid >> 4;   // 16 k x 16 mg
    int k = kc * 16 + kk;
    const float* Vn = V + (size_t)n * KK * MM;
    float p[8];
#pragma unroll
    for (int c = 0; c < 8; ++c) p[c] = 0.f;
    bool ok0 = (k - 1 >= 0), ok2 = (k + 1 < KK);
    const float* v0p = Vn + (size_t)(k - 1) * MM;
    const float* v1p = Vn + (size_t)k * MM;
    const float* v2p = Vn + (size_t)(k + 1) * MM;
    int mbase = mg * 24;
    for (int mi = 0; mi < 24; ++mi) {
        int m = mbase + mi;
        float a0 = ok0 ? v0p[m] : 0.f;
        float a1 = v1p[m];
        float a2 = ok2 ? v2p[m] : 0.f;
        const float4* w0 = (const float4*)&wt[(0 * MM + m) * 8];
        const float4* w1q = (const float4*)&wt[(1 * MM + m) * 8];
        const float4* w2q = (const float4*)&wt[(2 * MM + m) * 8];
        float4 x, y;
        x = w0[0]; y = w0[1];
        p[0] = fmaf(a0, x.x, p[0]); p[1] = fmaf(a0, x.y, p[1]);
        p[2] = fmaf(a0, x.z, p[2]); p[3] = fmaf(a0, x.w, p[3]);
        p[4] = fmaf(a0, y.x, p[4]); p[5] = fmaf(a0, y.y, p[5]);
        p[6] = fmaf(a0, y.z, p[6]); p[7] = fmaf(a0, y.w, p[7]);
        x = w1q[0]; y = w1q[1];
        p[0] = fmaf(a1, x.x, p[0]); p[1] = fmaf(a1, x.y, p[1]);
        p[2] = fmaf(a1, x.z, p[2]); p[3] = fmaf(a1, x.w, p[3]);
        p[4] = fmaf(a1, y.x, p[4]); p[5] = fmaf(a1, y.y, p[5]);
        p[6] = fmaf(a1, y.z, p[6]); p[7] = fmaf(a1, y.w, p[7]);
        x = w2q[0]; y = w2q[1];
        p[0] = fmaf(a2, x.x, p[0]); p[1] = fmaf(a2, x.y, p[1]);
        p[2] = fmaf(a2, x.z, p[2]); p[3] = fmaf(a2, x.w, p[3]);
        p[4] = fmaf(a2, y.x, p[4]); p[5] = fmaf(a2, y.y, p[5]);
        p[6] = fmaf(a2, y.z, p[6]); p[7] = fmaf(a2, y.w, p[7]);
    }
#pragma unroll
    for (int c = 0; c < 8; ++c) red[(kk * 16 + mg) * 8 + c] = p[c];
    if (tid < 16) dl[tid] = wsD[n * KK + kc * 16 + tid];
    __syncthreads();

    // BN + silu: 128 threads = 16 k x 8 c
    if (tid < 128) {
        int kk2 = tid & 15, c = tid >> 4;
        float s = 0.f;
#pragma unroll
        for (int mg2 = 0; mg2 < 16; ++mg2) s += red[(kk2 * 16 + mg2) * 8 + c];
        float xx = s + conv_b[c];
        float bn = (xx - bn_m[c]) * (bn_g[c] * rsqrtf(bn_v[c] + 1e-3f)) + bn_b[c];
        cvl[kk2 * 8 + c] = silu_f(bn);
    }
    __syncthreads();

    // q1 fold: 256 threads = 16 k x 16 j
    {
        int kk3 = tid & 15, j = tid >> 4;
        int k3 = kc * 16 + kk3;
        float q = fmaf(dl[kk3], w1[16 + j], b1[j]);
#pragma unroll
        for (int c = 0; c < 8; ++c) q = fmaf(cvl[kk3 * 8 + c], w1[(2 + c) * 16 + j], q);
        wsQ1[((size_t)(n * KK + k3)) * 16 + j] = q;
    }
    // qA fold: 32 threads = 16 k x 2 p
    if (tid < 32) {
        int kk4 = tid & 15, pp = tid >> 4;
        int k4 = kc * 16 + kk4;
        float q = fmaf(dl[kk4], aw1[2 + pp], ab1[pp]);
#pragma unroll
        for (int c = 0; c < 8; ++c) q = fmaf(cvl[kk4 * 8 + c], aw1[(2 + c) * 2 + pp], q);
        wsQA[(size_t)(n * KK + k4) * 2 + pp] = q;
    }
}

// ---------------- K3a: scores -> softmax -> normalized E_T + aux C ----------------
// Phase A: t-quad, w2/b2/w3 read from GLOBAL with uniform addresses (scalar K$),
// accumulators uncapped (NO min-waves launch bound -- caps spill, see R3/R4).
__global__ __launch_bounds__(256) void k_score(
    const float* __restrict__ w1, const float* __restrict__ w2g,
    const float* __restrict__ b2g, const float* __restrict__ w3g,
    const float* __restrict__ b3g, const float* __restrict__ aw1,
    const float* __restrict__ aw2g, const float* __restrict__ ab2g,
    const float* __restrict__ wsS, const float* __restrict__ wsQ1,
    const float* __restrict__ wsQA, float* __restrict__ wcg,
    float* __restrict__ ET) {
    __shared__ __align__(16) float sc[TCH * KK];   // 16 KB
    __shared__ __align__(16) float rl[16];

    int tid = threadIdx.x;
    int tb = blockIdx.x * TCH;
    int n = blockIdx.y;
    int nK = n * KK;

    if (tid < 16) rl[tid] = w1[tid] - w1[16 + tid];

    float b3v = b3g[0];
    int k = tid;
    float S_k = wsS[nK + k];
    float q1[16];
    {
        const float4* q1p = (const float4*)&wsQ1[(size_t)(nK + k) * 16];
#pragma unroll
        for (int g = 0; g < 4; ++g) {
            float4 qv = q1p[g];
            q1[4 * g + 0] = qv.x; q1[4 * g + 1] = qv.y;
            q1[4 * g + 2] = qv.z; q1[4 * g + 3] = qv.w;
        }
    }
    __syncthreads();

    // ---- phase A: scores, 4 t's at a time; w2 rows via uniform (scalar) loads ----
    for (int tq = 0; tq < TCH / 4; ++tq) {
        float s0 = (float)(tb + 4 * tq + 1) - S_k;
        float aA[16], aB[16], aC[16], aD[16];
#pragma unroll
        for (int j = 0; j < 16; ++j) { aA[j] = 0.f; aB[j] = 0.f; aC[j] = 0.f; aD[j] = 0.f; }
#pragma unroll
        for (int j1 = 0; j1 < 16; ++j1) {
            float r = rl[j1];
            float q = q1[j1];
            float hA = silu_f(fmaf(s0, r, q));
            float hB = silu_f(fmaf(s0 + 1.0f, r, q));
            float hC = silu_f(fmaf(s0 + 2.0f, r, q));
            float hD = silu_f(fmaf(s0 + 3.0f, r, q));
            const float4* wr = (const float4*)&w2g[j1 * 16];   // uniform -> s_load
#pragma unroll
            for (int g = 0; g < 4; ++g) {
                float4 w = wr[g];
                aA[4 * g + 0] = fmaf(hA, w.x, aA[4 * g + 0]);
                aA[4 * g + 1] = fmaf(hA, w.y, aA[4 * g + 1]);
                aA[4 * g + 2] = fmaf(hA, w.z, aA[4 * g + 2]);
                aA[4 * g + 3] = fmaf(hA, w.w, aA[4 * g + 3]);
                aB[4 * g + 0] = fmaf(hB, w.x, aB[4 * g + 0]);
                aB[4 * g + 1] = fmaf(hB, w.y, aB[4 * g + 1]);
                aB[4 * g + 2] = fmaf(hB, w.z, aB[4 * g + 2]);
                aB[4 * g + 3] = fmaf(hB, w.w, aB[4 * g + 3]);
                aC[4 * g + 0] = fmaf(hC, w.x, aC[4 * g + 0]);
                aC[4 * g + 1] = fmaf(hC, w.y, aC[4 * g + 1]);
                aC[4 * g + 2] = fmaf(hC, w.z, aC[4 * g + 2]);
                aC[4 * g + 3] = fmaf(hC, w.w, aC[4 * g + 3]);
                aD[4 * g + 0] = fmaf(hD, w.x, aD[4 * g + 0]);
                aD[4 * g + 1] = fmaf(hD, w.y, aD[4 * g + 1]);
                aD[4 * g + 2] = fmaf(hD, w.z, aD[4 * g + 2]);
                aD[4 * g + 3] = fmaf(hD, w.w, aD[4 * g + 3]);
            }
        }
        float scA = b3v, scB = b3v, scC = b3v, scD = b3v;
#pragma unroll
        for (int g = 0; g < 4; ++g) {
            float4 bq = *(const float4*)&b2g[4 * g];   // uniform -> s_load
            float4 wq = *(const float4*)&w3g[4 * g];   // uniform -> s_load
            scA += silu_f(aA[4 * g + 0] + bq.x) * wq.x + silu_f(aA[4 * g + 1] + bq.y) * wq.y +
                   silu_f(aA[4 * g + 2] + bq.z) * wq.z + silu_f(aA[4 * g + 3] + bq.w) * wq.w;
            scB += silu_f(aB[4 * g + 0] + bq.x) * wq.x + silu_f(aB[4 * g + 1] + bq.y) * wq.y +
                   silu_f(aB[4 * g + 2] + bq.z) * wq.z + silu_f(aB[4 * g + 3] + bq.w) * wq.w;
            scC += silu_f(aC[4 * g + 0] + bq.x) * wq.x + silu_f(aC[4 * g + 1] + bq.y) * wq.y +
                   silu_f(aC[4 * g + 2] + bq.z) * wq.z + silu_f(aC[4 * g + 3] + bq.w) * wq.w;
            scD += silu_f(aD[4 * g + 0] + bq.x) * wq.x + silu_f(aD[4 * g + 1] + bq.y) * wq.y +
                   silu_f(aD[4 * g + 2] + bq.z) * wq.z + silu_f(aD[4 * g + 3] + bq.w) * wq.w;
        }
        sc[(4 * tq + 0) * KK + k] = scA;
        sc[(4 * tq + 1) * KK + k] = scB;
        sc[(4 * tq + 2) * KK + k] = scC;
        sc[(4 * tq + 3) * KK + k] = scD;
    }
    __syncthreads();

    // ---- softmax over k (wave-parallel) + aux C; normalize in place ----
    {
        float rA0 = aw1[0] - aw1[2];
        float rA1 = aw1[1] - aw1[3];
        float aw200 = aw2g[0], aw201 = aw2g[1], aw210 = aw2g[2], aw211 = aw2g[3];
        float ab20 = ab2g[0], ab21 = ab2g[1];
        int wv = tid >> 6, lane = tid & 63;
        // preload per-lane softmax-phase data once (reused for all 4 t's)
        float S4[4]; float2 QA4[4];
#pragma unroll
        for (int j = 0; j < 4; ++j) {
            int kk2 = lane + 64 * j;
            S4[j] = wsS[nK + kk2];
            QA4[j] = *(const float2*)&wsQA[(size_t)(nK + kk2) * 2];
        }
#pragma unroll
        for (int i = 0; i < 4; ++i) {
            int t = wv * 4 + i;
            int tt = tb + t;
            float v0 = sc[t * KK + lane];
            float v1 = sc[t * KK + lane + 64];
            float v2 = sc[t * KK + lane + 128];
            float v3 = sc[t * KK + lane + 192];
            float mx = fmaxf(fmaxf(v0, v1), fmaxf(v2, v3));
#pragma unroll
            for (int off = 32; off >= 1; off >>= 1) mx = fmaxf(mx, __shfl_xor(mx, off));
            float e0 = __expf(v0 - mx), e1 = __expf(v1 - mx);
            float e2 = __expf(v2 - mx), e3 = __expf(v3 - mx);
            float ssum = e0 + e1 + e2 + e3;
            float wc0 = 0.f, wc1 = 0.f;
            float tc = (float)(tt + 1);
            float ear[4] = {e0, e1, e2, e3};
#pragma unroll
            for (int j = 0; j < 4; ++j) {
                float s = tc - S4[j];
                float a0 = silu_f(fmaf(s, rA0, QA4[j].x));
                float a1 = silu_f(fmaf(s, rA1, QA4[j].y));
                float c0 = silu_f(fmaf(a1, aw210, fmaf(a0, aw200, ab20)));
                float c1 = silu_f(fmaf(a1, aw211, fmaf(a0, aw201, ab21)));
                wc0 = fmaf(ear[j], c0, wc0);
                wc1 = fmaf(ear[j], c1, wc1);
            }
#pragma unroll
            for (int off = 32; off >= 1; off >>= 1) {
                ssum += __shfl_xor(ssum, off);
                wc0 += __shfl_xor(wc0, off);
                wc1 += __shfl_xor(wc1, off);
            }
            float inv = fast_rcp(ssum);
            sc[t * KK + lane]       = e0 * inv;
            sc[t * KK + lane + 64]  = e1 * inv;
            sc[t * KK + lane + 128] = e2 * inv;
            sc[t * KK + lane + 192] = e3 * inv;
            if (lane == 0 && tt < TT) {
                wcg[(size_t)(n * TT + tt) * 2]     = wc0 * inv;
                wcg[(size_t)(n * TT + tt) * 2 + 1] = wc1 * inv;
            }
        }
    }
    __syncthreads();

    // ---- write transposed E_T[n][k][t] (normalized) ----
    for (int idx = tid; idx < TCH * KK; idx += 256) {
        int k2 = idx >> 4, t2 = idx & 15;
        if (tb + t2 < TT)
            ET[((size_t)(nK + k2)) * TP + tb + t2] = sc[t2 * KK + k2];
    }
}

// ---------------- K3b: O[n,t,m] = sum_k E[t,k] V[k,m] + Caux@proj ----------------
// 384 threads, 1 m each: El reads are wave-uniform LDS broadcasts (cheap);
// 6 waves/block x ~4 blocks/CU -> high occupancy.
__global__ __launch_bounds__(384) void k_out(
    const float* __restrict__ V, const float* __restrict__ projw,
    const float* __restrict__ wcg, const float* __restrict__ ET,
    float* __restrict__ out) {
    __shared__ __align__(16) float El[KK * 16];    // 16 KB  [k][t]
    int tid = threadIdx.x;
    int tb = blockIdx.x * TOB;
    int n = blockIdx.y;
    int nK = n * KK;
    const float* Vn = V + (size_t)n * KK * MM;
    int m = tid;

    for (int i = tid; i < KK * 4; i += 384) {
        int kx = i >> 2, q = i & 3;
        *(float4*)&El[kx * 16 + 4 * q] =
            *(const float4*)(ET + (size_t)(nK + kx) * TP + tb + 4 * q);
    }
    __syncthreads();

    float acc[TOB];
#pragma unroll
    for (int t = 0; t < TOB; ++t) acc[t] = 0.f;

#pragma unroll 4
    for (int kx = 0; kx < KK; ++kx) {
        const float4* ep = (const float4*)&El[kx * 16];
        float4 e0 = ep[0], e1 = ep[1], e2 = ep[2], e3 = ep[3];
        float vv = Vn[(size_t)kx * MM + m];
        acc[0]  = fmaf(e0.x, vv, acc[0]);  acc[1]  = fmaf(e0.y, vv, acc[1]);
        acc[2]  = fmaf(e0.z, vv, acc[2]);  acc[3]  = fmaf(e0.w, vv, acc[3]);
        acc[4]  = fmaf(e1.x, vv, acc[4]);  acc[5]  = fmaf(e1.y, vv, acc[5]);
        acc[6]  = fmaf(e1.z, vv, acc[6]);  acc[7]  = fmaf(e1.w, vv, acc[7]);
        acc[8]  = fmaf(e2.x, vv, acc[8]);  acc[9]  = fmaf(e2.y, vv, acc[9]);
        acc[10] = fmaf(e2.z, vv, acc[10]); acc[11] = fmaf(e2.w, vv, acc[11]);
        acc[12] = fmaf(e3.x, vv, acc[12]); acc[13] = fmaf(e3.y, vv, acc[13]);
        acc[14] = fmaf(e3.z, vv, acc[14]); acc[15] = fmaf(e3.w, vv, acc[15]);
    }

    float pw0 = projw[m], pw1 = projw[MM + m];
#pragma unroll
    for (int t = 0; t < TOB; ++t) {
        int tt = tb + t;
        if (tt < TT) {
            float c0 = wcg[(size_t)(n * TT + tt) * 2];
            float c1 = wcg[(size_t)(n * TT + tt) * 2 + 1];
            out[((size_t)n * TT + tt) * MM + m] = acc[t] + c0 * pw0 + c1 * pw1;
        }
    }
}

extern "C" void kernel_launch(void* const* d_in, const int* in_sizes, int n_in,
                              void* d_out, int out_size, void* d_ws, size_t ws_size,
                              hipStream_t stream) {
    const float* V   = (const float*)d_in[0];
    const float* dur = (const float*)d_in[1];
    const float* cw  = (const float*)d_in[2];
    const float* cb  = (const float*)d_in[3];
    const float* bng = (const float*)d_in[4];
    const float* bnb = (const float*)d_in[5];
    const float* bnm = (const float*)d_in[6];
    const float* bnv = (const float*)d_in[7];
    const float* w1  = (const float*)d_in[8];
    const float* b1  = (const float*)d_in[9];
    const float* w2  = (const float*)d_in[10];
    const float* b2  = (const float*)d_in[11];
    const float* w3  = (const float*)d_in[12];
    const float* b3  = (const float*)d_in[13];
    const float* aw1 = (const float*)d_in[14];
    const float* ab1 = (const float*)d_in[15];
    const float* aw2 = (const float*)d_in[16];
    const float* ab2 = (const float*)d_in[17];
    const float* pw  = (const float*)d_in[18];
    float* out = (float*)d_out;
    float* ws = (float*)d_ws;

    float* wsS  = ws;                 // 4096
    float* wsD  = ws + 4096;          // 4096
    float* wsQ1 = ws + 8192;          // 65536
    float* wsQA = ws + 73728;         // 8192
    float* wcg  = ws + 81920;         // 32768 (N*T*2 = 32000 used)
    float* ET   = ws + 114688;        // N*K*TP floats (~16.5 MB)

    hipLaunchKernelGGL(k_scan, dim3(NN), dim3(KK), 0, stream, dur, wsS, wsD);
    hipLaunchKernelGGL(k_conv, dim3(16, NN), dim3(256), 0, stream, V, cw, cb, bng,
                       bnb, bnm, bnv, w1, b1, aw1, ab1, wsD, wsQ1, wsQA);
    hipLaunchKernelGGL(k_score, dim3((TT + TCH - 1) / TCH, NN), dim3(256), 0, stream,
                       w1, w2, b2, w3, b3, aw1, aw2, ab2, wsS, wsQ1, wsQA, wcg, ET);
    hipLaunchKernelGGL(k_out, dim3((TT + TOB - 1) / TOB, NN), dim3(384), 0, stream,
                       V, pw, wcg, ET, out);
}

// Round 7
// 165.663 us; speedup vs baseline: 1.0914x; 1.0914x over previous
//
#include <hip/hip_runtime.h>

#define NN 16
#define KK 256
#define TT 1000
#define MM 384
#define TCH 16     // t's per k_score block (63 blocks, tail-guarded)
#define TOB 28     // t's per k_out block (36*28 = 1008 = TP exactly)
#define TP 1008    // padded T stride for E_T (4032 B, 16B-aligned rows)

__device__ __forceinline__ float fast_rcp(float x) { return __builtin_amdgcn_rcpf(x); }
__device__ __forceinline__ float silu_f(float x) {
    float e = __expf(-x);
    return x * fast_rcp(1.0f + e);
}

// ---------------- K1: durations + exclusive cumsum ----------------
__global__ void k_scan(const float* __restrict__ dur_out,
                       float* __restrict__ wsS, float* __restrict__ wsD) {
    __shared__ float lds[KK];
    int n = blockIdx.x, k = threadIdx.x;
    float d = __expf(dur_out[n * KK + k]) - 1.0f;
    d = fmaxf(d, 0.0f);
    lds[k] = d;
    __syncthreads();
    float run = d;
    for (int off = 1; off < KK; off <<= 1) {
        float v = (k >= off) ? lds[k - off] : 0.0f;
        __syncthreads();
        run += v;
        lds[k] = run;
        __syncthreads();
    }
    wsS[n * KK + k] = run - d;
    wsD[n * KK + k] = d;
}

// ---------------- K2: conv1d(3,same)+BN+silu, fold into q1/qA ----------------
// One wave per k; lanes are m-major (6 m's each, stride 64) -> coalesced V reads.
// Weights in LDS transposed [c][tap][m] -> lane-stride-1 ds_read_b32, no conflicts.
__global__ __launch_bounds__(256) void k_conv(
    const float* __restrict__ V, const float* __restrict__ conv_w,
    const float* __restrict__ conv_b, const float* __restrict__ bn_g,
    const float* __restrict__ bn_b, const float* __restrict__ bn_m,
    const float* __restrict__ bn_v, const float* __restrict__ w1,
    const float* __restrict__ b1, const float* __restrict__ aw1,
    const float* __restrict__ ab1, const float* __restrict__ wsD,
    float* __restrict__ wsQ1, float* __restrict__ wsQA) {
    __shared__ float wt[8 * 3 * MM];   // 36 KB, [c][tap][m]
    int tid = threadIdx.x;
    int n = blockIdx.y;
    // load + transpose weights (global coalesced; LDS scatter is one-time)
    for (int i = tid; i < 3 * MM * 8; i += 256) {
        int tap = i / (MM * 8);
        int r = i - tap * (MM * 8);
        int m = r >> 3, c = r & 7;
        wt[(c * 3 + tap) * MM + m] = conv_w[i];
    }
    __syncthreads();

    int wv = tid >> 6, lane = tid & 63;
    int k = blockIdx.x * 4 + wv;
    const float* Vn = V + (size_t)n * KK * MM;

    float p[8];
#pragma unroll
    for (int c = 0; c < 8; ++c) p[c] = 0.f;

#pragma unroll
    for (int tap = 0; tap < 3; ++tap) {
        int kk = k + tap - 1;
        if (kk < 0 || kk >= KK) continue;   // wave-uniform branch
        const float* vrow = Vn + (size_t)kk * MM;
#pragma unroll
        for (int j = 0; j < 6; ++j) {
            int m = lane + 64 * j;
            float v = vrow[m];              // coalesced
#pragma unroll
            for (int c = 0; c < 8; ++c)
                p[c] = fmaf(v, wt[(c * 3 + tap) * MM + m], p[c]);
        }
    }
    // butterfly reduce over 64 lanes -> all lanes hold the sum
#pragma unroll
    for (int c = 0; c < 8; ++c) {
#pragma unroll
        for (int off = 32; off >= 1; off >>= 1) p[c] += __shfl_xor(p[c], off);
    }
    // BN + silu (all lanes, redundant but cheap)
    float cv[8];
#pragma unroll
    for (int c = 0; c < 8; ++c) {
        float xx = p[c] + conv_b[c];
        float bn = (xx - bn_m[c]) * (bn_g[c] * rsqrtf(bn_v[c] + 1e-3f)) + bn_b[c];
        cv[c] = silu_f(bn);
    }
    float d = wsD[n * KK + k];
    if (lane < 16) {
        int j = lane;
        float q = fmaf(d, w1[16 + j], b1[j]);
#pragma unroll
        for (int c = 0; c < 8; ++c) q = fmaf(cv[c], w1[(2 + c) * 16 + j], q);
        wsQ1[((size_t)(n * KK + k)) * 16 + j] = q;
    } else if (lane < 18) {
        int pp = lane - 16;
        float q = fmaf(d, aw1[2 + pp], ab1[pp]);
#pragma unroll
        for (int c = 0; c < 8; ++c) q = fmaf(cv[c], aw1[(2 + c) * 2 + pp], q);
        wsQA[(size_t)(n * KK + k) * 2 + pp] = q;
    }
}

// ---------------- K3a: scores -> softmax -> normalized E_T + aux C ----------------
// Phase A: t-quad, w2/b2/w3 read from GLOBAL with uniform addresses (scalar K$),
// accumulators uncapped (NO min-waves launch bound -- caps spill, see R3/R4).
__global__ __launch_bounds__(256) void k_score(
    const float* __restrict__ w1, const float* __restrict__ w2g,
    const float* __restrict__ b2g, const float* __restrict__ w3g,
    const float* __restrict__ b3g, const float* __restrict__ aw1,
    const float* __restrict__ aw2g, const float* __restrict__ ab2g,
    const float* __restrict__ wsS, const float* __restrict__ wsQ1,
    const float* __restrict__ wsQA, float* __restrict__ wcg,
    float* __restrict__ ET) {
    __shared__ __align__(16) float sc[TCH * KK];   // 16 KB
    __shared__ __align__(16) float rl[16];

    int tid = threadIdx.x;
    int tb = blockIdx.x * TCH;
    int n = blockIdx.y;
    int nK = n * KK;

    if (tid < 16) rl[tid] = w1[tid] - w1[16 + tid];

    float b3v = b3g[0];
    int k = tid;
    float S_k = wsS[nK + k];
    float q1[16];
    {
        const float4* q1p = (const float4*)&wsQ1[(size_t)(nK + k) * 16];
#pragma unroll
        for (int g = 0; g < 4; ++g) {
            float4 qv = q1p[g];
            q1[4 * g + 0] = qv.x; q1[4 * g + 1] = qv.y;
            q1[4 * g + 2] = qv.z; q1[4 * g + 3] = qv.w;
        }
    }
    __syncthreads();

    // ---- phase A: scores, 4 t's at a time; w2 rows via uniform (scalar) loads ----
    for (int tq = 0; tq < TCH / 4; ++tq) {
        float s0 = (float)(tb + 4 * tq + 1) - S_k;
        float aA[16], aB[16], aC[16], aD[16];
#pragma unroll
        for (int j = 0; j < 16; ++j) { aA[j] = 0.f; aB[j] = 0.f; aC[j] = 0.f; aD[j] = 0.f; }
#pragma unroll
        for (int j1 = 0; j1 < 16; ++j1) {
            float r = rl[j1];
            float q = q1[j1];
            float hA = silu_f(fmaf(s0, r, q));
            float hB = silu_f(fmaf(s0 + 1.0f, r, q));
            float hC = silu_f(fmaf(s0 + 2.0f, r, q));
            float hD = silu_f(fmaf(s0 + 3.0f, r, q));
            const float4* wr = (const float4*)&w2g[j1 * 16];   // uniform -> s_load
#pragma unroll
            for (int g = 0; g < 4; ++g) {
                float4 w = wr[g];
                aA[4 * g + 0] = fmaf(hA, w.x, aA[4 * g + 0]);
                aA[4 * g + 1] = fmaf(hA, w.y, aA[4 * g + 1]);
                aA[4 * g + 2] = fmaf(hA, w.z, aA[4 * g + 2]);
                aA[4 * g + 3] = fmaf(hA, w.w, aA[4 * g + 3]);
                aB[4 * g + 0] = fmaf(hB, w.x, aB[4 * g + 0]);
                aB[4 * g + 1] = fmaf(hB, w.y, aB[4 * g + 1]);
                aB[4 * g + 2] = fmaf(hB, w.z, aB[4 * g + 2]);
                aB[4 * g + 3] = fmaf(hB, w.w, aB[4 * g + 3]);
                aC[4 * g + 0] = fmaf(hC, w.x, aC[4 * g + 0]);
                aC[4 * g + 1] = fmaf(hC, w.y, aC[4 * g + 1]);
                aC[4 * g + 2] = fmaf(hC, w.z, aC[4 * g + 2]);
                aC[4 * g + 3] = fmaf(hC, w.w, aC[4 * g + 3]);
                aD[4 * g + 0] = fmaf(hD, w.x, aD[4 * g + 0]);
                aD[4 * g + 1] = fmaf(hD, w.y, aD[4 * g + 1]);
                aD[4 * g + 2] = fmaf(hD, w.z, aD[4 * g + 2]);
                aD[4 * g + 3] = fmaf(hD, w.w, aD[4 * g + 3]);
            }
        }
        float scA = b3v, scB = b3v, scC = b3v, scD = b3v;
#pragma unroll
        for (int g = 0; g < 4; ++g) {
            float4 bq = *(const float4*)&b2g[4 * g];   // uniform -> s_load
            float4 wq = *(const float4*)&w3g[4 * g];   // uniform -> s_load
            scA += silu_f(aA[4 * g + 0] + bq.x) * wq.x + silu_f(aA[4 * g + 1] + bq.y) * wq.y +
                   silu_f(aA[4 * g + 2] + bq.z) * wq.z + silu_f(aA[4 * g + 3] + bq.w) * wq.w;
            scB += silu_f(aB[4 * g + 0] + bq.x) * wq.x + silu_f(aB[4 * g + 1] + bq.y) * wq.y +
                   silu_f(aB[4 * g + 2] + bq.z) * wq.z + silu_f(aB[4 * g + 3] + bq.w) * wq.w;
            scC += silu_f(aC[4 * g + 0] + bq.x) * wq.x + silu_f(aC[4 * g + 1] + bq.y) * wq.y +
                   silu_f(aC[4 * g + 2] + bq.z) * wq.z + silu_f(aC[4 * g + 3] + bq.w) * wq.w;
            scD += silu_f(aD[4 * g + 0] + bq.x) * wq.x + silu_f(aD[4 * g + 1] + bq.y) * wq.y +
                   silu_f(aD[4 * g + 2] + bq.z) * wq.z + silu_f(aD[4 * g + 3] + bq.w) * wq.w;
        }
        sc[(4 * tq + 0) * KK + k] = scA;
        sc[(4 * tq + 1) * KK + k] = scB;
        sc[(4 * tq + 2) * KK + k] = scC;
        sc[(4 * tq + 3) * KK + k] = scD;
    }
    __syncthreads();

    // ---- softmax over k (wave-parallel) + aux C; normalize in place ----
    {
        float rA0 = aw1[0] - aw1[2];
        float rA1 = aw1[1] - aw1[3];
        float aw200 = aw2g[0], aw201 = aw2g[1], aw210 = aw2g[2], aw211 = aw2g[3];
        float ab20 = ab2g[0], ab21 = ab2g[1];
        int wv = tid >> 6, lane = tid & 63;
        float S4[4]; float2 QA4[4];
#pragma unroll
        for (int j = 0; j < 4; ++j) {
            int kk2 = lane + 64 * j;
            S4[j] = wsS[nK + kk2];
            QA4[j] = *(const float2*)&wsQA[(size_t)(nK + kk2) * 2];
        }
#pragma unroll
        for (int i = 0; i < 4; ++i) {
            int t = wv * 4 + i;
            int tt = tb + t;
            float v0 = sc[t * KK + lane];
            float v1 = sc[t * KK + lane + 64];
            float v2 = sc[t * KK + lane + 128];
            float v3 = sc[t * KK + lane + 192];
            float mx = fmaxf(fmaxf(v0, v1), fmaxf(v2, v3));
#pragma unroll
            for (int off = 32; off >= 1; off >>= 1) mx = fmaxf(mx, __shfl_xor(mx, off));
            float e0 = __expf(v0 - mx), e1 = __expf(v1 - mx);
            float e2 = __expf(v2 - mx), e3 = __expf(v3 - mx);
            float ssum = e0 + e1 + e2 + e3;
            float wc0 = 0.f, wc1 = 0.f;
            float tc = (float)(tt + 1);
            float ear[4] = {e0, e1, e2, e3};
#pragma unroll
            for (int j = 0; j < 4; ++j) {
                float s = tc - S4[j];
                float a0 = silu_f(fmaf(s, rA0, QA4[j].x));
                float a1 = silu_f(fmaf(s, rA1, QA4[j].y));
                float c0 = silu_f(fmaf(a1, aw210, fmaf(a0, aw200, ab20)));
                float c1 = silu_f(fmaf(a1, aw211, fmaf(a0, aw201, ab21)));
                wc0 = fmaf(ear[j], c0, wc0);
                wc1 = fmaf(ear[j], c1, wc1);
            }
#pragma unroll
            for (int off = 32; off >= 1; off >>= 1) {
                ssum += __shfl_xor(ssum, off);
                wc0 += __shfl_xor(wc0, off);
                wc1 += __shfl_xor(wc1, off);
            }
            float inv = fast_rcp(ssum);
            sc[t * KK + lane]       = e0 * inv;
            sc[t * KK + lane + 64]  = e1 * inv;
            sc[t * KK + lane + 128] = e2 * inv;
            sc[t * KK + lane + 192] = e3 * inv;
            if (lane == 0 && tt < TT) {
                wcg[(size_t)(n * TT + tt) * 2]     = wc0 * inv;
                wcg[(size_t)(n * TT + tt) * 2 + 1] = wc1 * inv;
            }
        }
    }
    __syncthreads();

    // ---- write transposed E_T[n][k][t] (normalized) ----
    for (int idx = tid; idx < TCH * KK; idx += 256) {
        int k2 = idx >> 4, t2 = idx & 15;
        if (tb + t2 < TT)
            ET[((size_t)(nK + k2)) * TP + tb + t2] = sc[t2 * KK + k2];
    }
}

// ---------------- K3b: O[n,t,m] = sum_k E[t,k] V[k,m] + Caux@proj ----------------
// E rows read via wave-uniform addresses -> scalar K$ (s_load), zero LDS.
// 384 threads, 1 m each; FMA uses 1 SGPR operand (legal).
__global__ __launch_bounds__(384) void k_out(
    const float* __restrict__ V, const float* __restrict__ projw,
    const float* __restrict__ wcg, const float* __restrict__ ET,
    float* __restrict__ out) {
    int tid = threadIdx.x;
    int tb = blockIdx.x * TOB;
    int n = blockIdx.y;
    int nK = n * KK;
    const float* Vn = V + (size_t)n * KK * MM;
    const float* Eb = ET + (size_t)nK * TP + tb;
    int m = tid;

    float acc[TOB];
#pragma unroll
    for (int t = 0; t < TOB; ++t) acc[t] = 0.f;

    for (int kx = 0; kx < KK; ++kx) {
        const float4* ep = (const float4*)(Eb + (size_t)kx * TP);  // uniform -> s_load
        float vv = Vn[(size_t)kx * MM + m];
#pragma unroll
        for (int q = 0; q < TOB / 4; ++q) {
            float4 e = ep[q];
            acc[4 * q + 0] = fmaf(e.x, vv, acc[4 * q + 0]);
            acc[4 * q + 1] = fmaf(e.y, vv, acc[4 * q + 1]);
            acc[4 * q + 2] = fmaf(e.z, vv, acc[4 * q + 2]);
            acc[4 * q + 3] = fmaf(e.w, vv, acc[4 * q + 3]);
        }
    }

    float pw0 = projw[m], pw1 = projw[MM + m];
#pragma unroll
    for (int t = 0; t < TOB; ++t) {
        int tt = tb + t;
        if (tt < TT) {
            float c0 = wcg[(size_t)(n * TT + tt) * 2];
            float c1 = wcg[(size_t)(n * TT + tt) * 2 + 1];
            out[((size_t)n * TT + tt) * MM + m] = acc[t] + c0 * pw0 + c1 * pw1;
        }
    }
}

extern "C" void kernel_launch(void* const* d_in, const int* in_sizes, int n_in,
                              void* d_out, int out_size, void* d_ws, size_t ws_size,
                              hipStream_t stream) {
    const float* V   = (const float*)d_in[0];
    const float* dur = (const float*)d_in[1];
    const float* cw  = (const float*)d_in[2];
    const float* cb  = (const float*)d_in[3];
    const float* bng = (const float*)d_in[4];
    const float* bnb = (const float*)d_in[5];
    const float* bnm = (const float*)d_in[6];
    const float* bnv = (const float*)d_in[7];
    const float* w1  = (const float*)d_in[8];
    const float* b1  = (const float*)d_in[9];
    const float* w2  = (const float*)d_in[10];
    const float* b2  = (const float*)d_in[11];
    const float* w3  = (const float*)d_in[12];
    const float* b3  = (const float*)d_in[13];
    const float* aw1 = (const float*)d_in[14];
    const float* ab1 = (const float*)d_in[15];
    const float* aw2 = (const float*)d_in[16];
    const float* ab2 = (const float*)d_in[17];
    const float* pw  = (const float*)d_in[18];
    float* out = (float*)d_out;
    float* ws = (float*)d_ws;

    float* wsS  = ws;                 // 4096
    float* wsD  = ws + 4096;          // 4096
    float* wsQ1 = ws + 8192;          // 65536
    float* wsQA = ws + 73728;         // 8192
    float* wcg  = ws + 81920;         // 32768 (N*T*2 = 32000 used)
    float* ET   = ws + 114688;        // N*K*TP floats (~16.5 MB)

    hipLaunchKernelGGL(k_scan, dim3(NN), dim3(KK), 0, stream, dur, wsS, wsD);
    hipLaunchKernelGGL(k_conv, dim3(KK / 4, NN), dim3(256), 0, stream, V, cw, cb,
                       bng, bnb, bnm, bnv, w1, b1, aw1, ab1, wsD, wsQ1, wsQA);
    hipLaunchKernelGGL(k_score, dim3((TT + TCH - 1) / TCH, NN), dim3(256), 0, stream,
                       w1, w2, b2, w3, b3, aw1, aw2, ab2, wsS, wsQ1, wsQA, wcg, ET);
    hipLaunchKernelGGL(k_out, dim3((TT + TOB - 1) / TOB, NN), dim3(384), 0, stream,
                       V, pw, wcg, ET, out);
}